// Round 13
// baseline (636.371 us; speedup 1.0000x reference)
//
#include <hip/hip_runtime.h>

#define EMB 64
constexpr int N_LAYERS = 3;
constexpr int OUT_D = EMB * (N_LAYERS + 1);  // 256
constexpr int SUBR = 512;      // rows per bucket
constexpr int RSHIFT = 9;      // log2(SUBR)
constexpr int MAXBUK = 256;    // supports N <= 131072 at SUBR=512
constexpr int PAD = 16;        // ints per counter line (64B)
constexpr int CHUNK = 4096;    // edges per partition block
constexpr int EPT = CHUNK / 256;  // 16 edges/thread (register-staged)
constexpr int NSL = 8;         // column slices (16384 cols = 2MB egobf each)
constexpr int SLSHIFT = 14;    // col>>14 -> slice

__device__ __forceinline__ float readlane_f(float v, int l) {
  return __int_as_float(__builtin_amdgcn_readlane(__float_as_int(v), l));
}
__device__ __forceinline__ int readlane_i(int v, int l) {
  return __builtin_amdgcn_readlane(v, l);
}
// f32 -> bf16 round-to-nearest-even (finite values)
__device__ __forceinline__ unsigned short f32_to_bf16(float f) {
  unsigned x = __float_as_uint(f);
  return (unsigned short)((x + 0x7FFF + ((x >> 16) & 1)) >> 16);
}
// bf16 bits -> f32 (exact)
__device__ __forceinline__ float bf16_to_f32(unsigned short u) {
  return __uint_as_float(((unsigned)u) << 16);
}

// ego[r][d] = masked embedding; also bf16 shadow + block 0 of all_emb [N][256]
// NOTE: launched AFTER the CSR build because tmp aliases all_emb.
__global__ void init_ego_kernel(const float* __restrict__ ue, const float* __restrict__ ie,
                                const int* __restrict__ usz, const int* __restrict__ isz,
                                float* __restrict__ ego, unsigned short* __restrict__ egobf,
                                float* __restrict__ all_emb, int n_users, int n_total) {
  int idx = blockIdx.x * blockDim.x + threadIdx.x;
  if (idx >= n_total * EMB) return;
  int r = idx >> 6, d = idx & 63;
  float v; int sz;
  if (r < n_users) {
    v = ue[idx];
    sz = usz[r];
  } else {
    int ri = r - n_users;
    v = ie[ri * EMB + d];
    sz = isz[ri];
  }
  v = (d < sz) ? v : 0.0f;
  ego[idx] = v;
  egobf[idx] = f32_to_bf16(v);
  all_emb[(size_t)r * OUT_D + d] = v;
}

// ---------- bucket histogram: LDS-aggregated, padded global flush ----------
__global__ __launch_bounds__(256) void bucket_hist_kernel(const int* __restrict__ rows,
                                                          int* __restrict__ bcnt_pad,
                                                          int nnz, int nbuk) {
  __shared__ int h[MAXBUK];
  for (int i = threadIdx.x; i < nbuk; i += 256) h[i] = 0;
  __syncthreads();
  int i = blockIdx.x * blockDim.x + threadIdx.x;
  int stride = gridDim.x * blockDim.x;
  for (; i < nnz; i += stride) atomicAdd(&h[rows[i] >> RSHIFT], 1);
  __syncthreads();
  for (int b = threadIdx.x; b < nbuk; b += 256)
    if (h[b]) atomicAdd(&bcnt_pad[b * PAD], h[b]);
}

// ---------- exclusive scan of padded counts -> bbase + padded cursors ----------
__global__ __launch_bounds__(512) void bucket_scan_kernel(const int* __restrict__ bcnt_pad,
                                                          int* __restrict__ bbase,
                                                          int* __restrict__ bcursor_pad,
                                                          int nbuk) {
  __shared__ int vals[MAXBUK];
  __shared__ int part[512];
  int t = threadIdx.x;
  for (int i = t; i < nbuk; i += 512) vals[i] = bcnt_pad[i * PAD];
  __syncthreads();
  int per = (nbuk + 511) / 512;
  int s0 = t * per;
  int lsum = 0;
  for (int i = 0; i < per; ++i) {
    int idx = s0 + i;
    if (idx < nbuk) lsum += vals[idx];
  }
  part[t] = lsum;
  __syncthreads();
  if (t == 0) {
    int acc = 0;
    for (int i = 0; i < 512; ++i) {
      int x = part[i];
      part[i] = acc;
      acc += x;
    }
  }
  __syncthreads();
  int run = part[t];
  for (int i = 0; i < per; ++i) {
    int idx = s0 + i;
    if (idx < nbuk) {
      bbase[idx] = run;
      bcursor_pad[idx * PAD] = run;
      run += vals[idx];
    }
  }
  if (t == 511) bbase[nbuk] = run;
}

// ---------- 3-phase LDS-staged partition into 512-row buckets ----------
__global__ __launch_bounds__(256) void partition_lds_kernel(
    const float* __restrict__ vals, const int* __restrict__ rows,
    const int* __restrict__ cols, int* __restrict__ bcursor_pad,
    int2* __restrict__ tmp, int nnz, int nbuk) {
  __shared__ int h[MAXBUK];
  __shared__ int cur[MAXBUK];
  for (int i = threadIdx.x; i < nbuk; i += 256) h[i] = 0;
  __syncthreads();

  int base = blockIdx.x * CHUNK;
  int rw[EPT], cl[EPT];
  float vl[EPT];
#pragma unroll
  for (int u = 0; u < EPT; ++u) {
    int ii = base + u * 256 + (int)threadIdx.x;
    bool ok = ii < nnz;
    rw[u] = ok ? rows[ii] : -1;
    cl[u] = ok ? cols[ii] : 0;
    vl[u] = ok ? vals[ii] : 0.0f;
    if (ok) atomicAdd(&h[rw[u] >> RSHIFT], 1);
  }
  __syncthreads();
  for (int b = threadIdx.x; b < nbuk; b += 256) {
    int c = h[b];
    cur[b] = c ? atomicAdd(&bcursor_pad[b * PAD], c) : 0;
  }
  __syncthreads();
#pragma unroll
  for (int u = 0; u < EPT; ++u) {
    if (rw[u] >= 0) {
      int b = rw[u] >> RSHIFT;
      int pos = atomicAdd(&cur[b], 1);
      tmp[pos] = make_int2(__float_as_int(vl[u]),
                           ((rw[u] & (SUBR - 1)) << 17) | cl[u]);
    }
  }
}

// ---------- per-bucket sort by (row_low, col_slice) -> CSR ----------
// Slice-grouped edges give temporal column locality in SpMM: concurrently
// resident row-waves all gather slice 0 first, then slice 1, ... so each
// XCD's 4MB L2 holds ~one 2MB egobf slice at a time instead of 12.8MB.
__global__ __launch_bounds__(256) void bucket_sort_kernel(
    const int2* __restrict__ tmp, const int* __restrict__ bbase,
    int2* __restrict__ edges, int* __restrict__ row_ptr, int nrows) {
  __shared__ int h[SUBR * NSL];   // 16KB: counts then cursors
  __shared__ int ex[SUBR * NSL];  // 16KB: exclusive prefix
  __shared__ int part[256];
  int b = blockIdx.x;
  int s = bbase[b], e = bbase[b + 1];
  int t = threadIdx.x;
  for (int j = t; j < SUBR * NSL; j += 256) h[j] = 0;
  __syncthreads();
  for (int i = s + t; i < e; i += 256) {
    int y = tmp[i].y;
    int key = ((y >> 17) << 3) | (((unsigned)(y & 0x1FFFF)) >> SLSHIFT);
    atomicAdd(&h[key], 1);
  }
  __syncthreads();
  // parallel exclusive scan of 4096 counters
  constexpr int PER = SUBR * NSL / 256;  // 16
  {
    int lsum = 0;
#pragma unroll
    for (int j = 0; j < PER; ++j) lsum += h[t * PER + j];
    part[t] = lsum;
  }
  __syncthreads();
  if (t == 0) {
    int acc = 0;
    for (int i = 0; i < 256; ++i) {
      int x = part[i];
      part[i] = acc;
      acc += x;
    }
  }
  __syncthreads();
  {
    int run = part[t];
#pragma unroll
    for (int j = 0; j < PER; ++j) {
      ex[t * PER + j] = run;
      run += h[t * PER + j];
    }
  }
  __syncthreads();
  int r0 = b << RSHIFT;
  int total = e - s;
  for (int j = t; j <= SUBR; j += 256) {
    int r = r0 + j;
    if ((j < SUBR && r < nrows) || r == nrows) {
      int v = (j < SUBR) ? ex[j * NSL] : total;
      row_ptr[r] = s + v;
    }
  }
  for (int j = t; j < SUBR * NSL; j += 256) h[j] = ex[j];  // cursors
  __syncthreads();
  for (int i = s + t; i < e; i += 256) {
    int2 tv = tmp[i];
    int y = tv.y;
    int key = ((y >> 17) << 3) | (((unsigned)(y & 0x1FFFF)) >> SLSHIFT);
    int p = atomicAdd(&h[key], 1);
    edges[s + p] = make_int2(tv.x, y & 0x1FFFF);
  }
}

// ---------- CSR SpMM: one wave per row, lane = dim, bf16 gathers ----------
__global__ __launch_bounds__(256) void spmm_csr_kernel(
    const int* __restrict__ rp, const int2* __restrict__ edges,
    const unsigned short* __restrict__ egobf, float* __restrict__ side,
    int nrows) {
  int lane = threadIdx.x & 63;
  int r = blockIdx.x * (blockDim.x >> 6) + (threadIdx.x >> 6);
  if (r >= nrows) return;
  int start = rp[r], end = rp[r + 1];
  float acc = 0.0f;
  for (int base = start; base < end; base += 64) {
    int m = end - base;
    if (m > 64) m = 64;
    int2 e = (base + lane < end) ? edges[base + lane] : make_int2(0, 0);
    float v_l = __int_as_float(e.x);
    int c_l = e.y;
    int kk = 0;
    for (; kk + 8 <= m; kk += 8) {
      int c[8];
      float v[8], x[8];
#pragma unroll
      for (int u = 0; u < 8; ++u) {
        c[u] = readlane_i(c_l, kk + u);
        v[u] = readlane_f(v_l, kk + u);
      }
#pragma unroll
      for (int u = 0; u < 8; ++u)
        x[u] = bf16_to_f32(egobf[(size_t)c[u] * EMB + lane]);
#pragma unroll
      for (int u = 0; u < 8; ++u) acc = fmaf(v[u], x[u], acc);
    }
    for (; kk < m; ++kk) {
      int c = readlane_i(c_l, kk);
      float v = readlane_f(v_l, kk);
      acc = fmaf(v, bf16_to_f32(egobf[(size_t)c * EMB + lane]), acc);
    }
  }
  side[(size_t)r * EMB + lane] = acc;
}

// per row: sum = side@Wgc + bgc ; bi = (ego*side)@Wbi + bbi ;
// ego_new = leaky_relu(sum+bi, 0.2) (UNNORMALIZED -> ego/egobf);
// all_emb[:, col_off:+64] = ego_new / max(||ego_new||, 1e-12)
__global__ __launch_bounds__(256) void layer_fused_kernel(
    const float* __restrict__ side, float* ego, unsigned short* __restrict__ egobf,
    const float* __restrict__ Wgc, const float* __restrict__ bgc,
    const float* __restrict__ Wbi, const float* __restrict__ bbi,
    float* __restrict__ all_emb, int nrows, int col_off) {
  int lane = threadIdx.x & 63;
  float wgc[EMB], wbi[EMB];
#pragma unroll
  for (int kk = 0; kk < EMB; ++kk) {
    wgc[kk] = Wgc[kk * EMB + lane];
    wbi[kk] = Wbi[kk * EMB + lane];
  }
  float bg = bgc[lane], bb = bbi[lane];
  int wid = blockIdx.x * (blockDim.x >> 6) + (threadIdx.x >> 6);
  int nw = gridDim.x * (blockDim.x >> 6);
  for (int r = wid; r < nrows; r += nw) {
    float s = side[(size_t)r * EMB + lane];
    float e = ego[(size_t)r * EMB + lane];
    float es = e * s;
    float g0 = 0.f, g1 = 0.f, g2 = 0.f, g3 = 0.f;
    float h0 = 0.f, h1 = 0.f, h2 = 0.f, h3 = 0.f;
#pragma unroll
    for (int kk = 0; kk < EMB; kk += 4) {
      g0 = fmaf(readlane_f(s, kk + 0), wgc[kk + 0], g0);
      g1 = fmaf(readlane_f(s, kk + 1), wgc[kk + 1], g1);
      g2 = fmaf(readlane_f(s, kk + 2), wgc[kk + 2], g2);
      g3 = fmaf(readlane_f(s, kk + 3), wgc[kk + 3], g3);
      h0 = fmaf(readlane_f(es, kk + 0), wbi[kk + 0], h0);
      h1 = fmaf(readlane_f(es, kk + 1), wbi[kk + 1], h1);
      h2 = fmaf(readlane_f(es, kk + 2), wbi[kk + 2], h2);
      h3 = fmaf(readlane_f(es, kk + 3), wbi[kk + 3], h3);
    }
    float o = (((g0 + g1) + (g2 + g3)) + bg) + (((h0 + h1) + (h2 + h3)) + bb);
    o = (o >= 0.0f) ? o : 0.2f * o;
    ego[(size_t)r * EMB + lane] = o;
    egobf[(size_t)r * EMB + lane] = f32_to_bf16(o);
    float sq = o * o;
#pragma unroll
    for (int off = 32; off; off >>= 1) sq += __shfl_xor(sq, off, 64);
    float norm = fmaxf(sqrtf(sq), 1e-12f);
    all_emb[(size_t)r * OUT_D + col_off + lane] = o / norm;
  }
}

__global__ void gather_out_kernel(const float* __restrict__ all_emb,
                                  const int* __restrict__ users,
                                  const int* __restrict__ pos,
                                  const int* __restrict__ neg,
                                  float* __restrict__ out, int n_users, int B) {
  int row = blockIdx.x;
  int sec = blockIdx.y;
  int t = threadIdx.x;
  int src;
  if (sec == 0) src = users[row];
  else if (sec == 1) src = n_users + pos[row];
  else src = n_users + neg[row];
  out[((size_t)sec * B + row) * OUT_D + t] = all_emb[(size_t)src * OUT_D + t];
}

extern "C" void kernel_launch(void* const* d_in, const int* in_sizes, int n_in,
                              void* d_out, int out_size, void* d_ws, size_t ws_size,
                              hipStream_t stream) {
  const float* user_emb = (const float*)d_in[0];
  const float* item_emb = (const float*)d_in[1];
  const float* W_gc = (const float*)d_in[2];
  const float* b_gc = (const float*)d_in[3];
  const float* W_bi = (const float*)d_in[4];
  const float* b_bi = (const float*)d_in[5];
  const float* adj_vals = (const float*)d_in[6];
  const int* adj_rows = (const int*)d_in[7];
  const int* adj_cols = (const int*)d_in[8];
  const int* user_sizes = (const int*)d_in[9];
  const int* item_sizes = (const int*)d_in[10];
  const int* users = (const int*)d_in[11];
  const int* pos_items = (const int*)d_in[12];
  const int* neg_items = (const int*)d_in[13];

  const int n_users = in_sizes[9];
  const int n_items = in_sizes[10];
  const int N = n_users + n_items;
  const int nnz = in_sizes[6];
  const int B = in_sizes[11];
  const int nbuk = (N + SUBR - 1) / SUBR;  // 196 for N=100000

  // workspace layout:
  // all_emb [N*256]f (tmp int2[nnz] aliases its head during build)
  // | ego [N*64]f | side [N*64]f | row_ptr [N+1]i | bbase [nbuk+1]i |
  // bcnt_pad [nbuk*PAD]i | bcursor_pad [nbuk*PAD]i | (align 8) edges [nnz]int2
  // | egobf [N*64]u16
  float* all_emb = (float*)d_ws;
  float* ego = all_emb + (size_t)N * OUT_D;
  float* side = ego + (size_t)N * EMB;
  int* row_ptr = (int*)(side + (size_t)N * EMB);
  int* bbase = row_ptr + (N + 1);
  int* bcnt_pad = bbase + (nbuk + 1);
  int* bcursor_pad = bcnt_pad + (size_t)nbuk * PAD;
  int2* edges = (int2*)((((uintptr_t)(bcursor_pad + (size_t)nbuk * PAD)) + 7) &
                        ~(uintptr_t)7);
  unsigned short* egobf = (unsigned short*)(edges + nnz);
  int2* tmp = (int2*)all_emb;  // aliased; init_ego runs after the build

  // --- build CSR sorted by (row, col_slice) ---
  hipMemsetAsync(bcnt_pad, 0, (size_t)nbuk * PAD * sizeof(int), stream);
  hipLaunchKernelGGL(bucket_hist_kernel, dim3(512), dim3(256), 0, stream,
                     adj_rows, bcnt_pad, nnz, nbuk);
  hipLaunchKernelGGL(bucket_scan_kernel, dim3(1), dim3(512), 0, stream,
                     bcnt_pad, bbase, bcursor_pad, nbuk);
  {
    int nchunks = (nnz + CHUNK - 1) / CHUNK;
    hipLaunchKernelGGL(partition_lds_kernel, dim3(nchunks), dim3(256), 0,
                       stream, adj_vals, adj_rows, adj_cols, bcursor_pad, tmp,
                       nnz, nbuk);
  }
  hipLaunchKernelGGL(bucket_sort_kernel, dim3(nbuk), dim3(256), 0, stream, tmp,
                     bbase, edges, row_ptr, N);

  // --- init ego (+bf16 shadow) + all_emb block 0 ---
  {
    int total = N * EMB;
    hipLaunchKernelGGL(init_ego_kernel, dim3((total + 255) / 256), dim3(256), 0,
                       stream, user_emb, item_emb, user_sizes, item_sizes, ego,
                       egobf, all_emb, n_users, N);
  }

  // --- 3 propagation layers ---
  for (int k = 0; k < N_LAYERS; ++k) {
    hipLaunchKernelGGL(spmm_csr_kernel, dim3((N + 3) / 4), dim3(256), 0, stream,
                       row_ptr, edges, egobf, side, N);
    hipLaunchKernelGGL(layer_fused_kernel, dim3(4096), dim3(256), 0, stream,
                       side, ego, egobf, W_gc + k * EMB * EMB, b_gc + k * EMB,
                       W_bi + k * EMB * EMB, b_bi + k * EMB, all_emb, N,
                       (k + 1) * EMB);
  }

  hipLaunchKernelGGL(gather_out_kernel, dim3(B, 3), dim3(256), 0, stream,
                     all_emb, users, pos_items, neg_items, (float*)d_out,
                     n_users, B);
}

// Round 15
// 635.664 us; speedup vs baseline: 1.0011x; 1.0011x over previous
//
#include <hip/hip_runtime.h>

#define EMB 64
constexpr int N_LAYERS = 3;
constexpr int OUT_D = EMB * (N_LAYERS + 1);  // 256
constexpr int SUBR = 512;      // rows per bucket
constexpr int RSHIFT = 9;      // log2(SUBR)
constexpr int MAXBUK = 256;    // supports N <= 131072 at SUBR=512
constexpr int PAD = 16;        // ints per counter line (64B)
constexpr int CHUNK = 4096;    // edges per partition block
constexpr int EPT = CHUNK / 256;  // 16 edges/thread (register-staged)

__device__ __forceinline__ float readlane_f(float v, int l) {
  return __int_as_float(__builtin_amdgcn_readlane(__float_as_int(v), l));
}
__device__ __forceinline__ int readlane_i(int v, int l) {
  return __builtin_amdgcn_readlane(v, l);
}
// f32 -> bf16 round-to-nearest-even (finite values)
__device__ __forceinline__ unsigned short f32_to_bf16(float f) {
  unsigned x = __float_as_uint(f);
  return (unsigned short)((x + 0x7FFF + ((x >> 16) & 1)) >> 16);
}
// bf16 bits -> f32 (exact)
__device__ __forceinline__ float bf16_to_f32(unsigned short u) {
  return __uint_as_float(((unsigned)u) << 16);
}

// ego[r][d] = masked embedding; also bf16 shadow + block 0 of all_emb [N][256]
// NOTE: launched AFTER the CSR build because tmp aliases all_emb.
__global__ void init_ego_kernel(const float* __restrict__ ue, const float* __restrict__ ie,
                                const int* __restrict__ usz, const int* __restrict__ isz,
                                float* __restrict__ ego, unsigned short* __restrict__ egobf,
                                float* __restrict__ all_emb, int n_users, int n_total) {
  int idx = blockIdx.x * blockDim.x + threadIdx.x;
  if (idx >= n_total * EMB) return;
  int r = idx >> 6, d = idx & 63;
  float v; int sz;
  if (r < n_users) {
    v = ue[idx];
    sz = usz[r];
  } else {
    int ri = r - n_users;
    v = ie[ri * EMB + d];
    sz = isz[ri];
  }
  v = (d < sz) ? v : 0.0f;
  ego[idx] = v;
  egobf[idx] = f32_to_bf16(v);
  all_emb[(size_t)r * OUT_D + d] = v;
}

// ---------- bucket histogram: LDS-aggregated, padded global flush ----------
__global__ __launch_bounds__(256) void bucket_hist_kernel(const int* __restrict__ rows,
                                                          int* __restrict__ bcnt_pad,
                                                          int nnz, int nbuk) {
  __shared__ int h[MAXBUK];
  for (int i = threadIdx.x; i < nbuk; i += 256) h[i] = 0;
  __syncthreads();
  int i = blockIdx.x * blockDim.x + threadIdx.x;
  int stride = gridDim.x * blockDim.x;
  for (; i < nnz; i += stride) atomicAdd(&h[rows[i] >> RSHIFT], 1);
  __syncthreads();
  for (int b = threadIdx.x; b < nbuk; b += 256)
    if (h[b]) atomicAdd(&bcnt_pad[b * PAD], h[b]);
}

// ---------- exclusive scan of padded counts -> bbase + padded cursors ----------
__global__ __launch_bounds__(512) void bucket_scan_kernel(const int* __restrict__ bcnt_pad,
                                                          int* __restrict__ bbase,
                                                          int* __restrict__ bcursor_pad,
                                                          int nbuk) {
  __shared__ int vals[MAXBUK];
  __shared__ int part[512];
  int t = threadIdx.x;
  for (int i = t; i < nbuk; i += 512) vals[i] = bcnt_pad[i * PAD];
  __syncthreads();
  int per = (nbuk + 511) / 512;
  int s0 = t * per;
  int lsum = 0;
  for (int i = 0; i < per; ++i) {
    int idx = s0 + i;
    if (idx < nbuk) lsum += vals[idx];
  }
  part[t] = lsum;
  __syncthreads();
  if (t == 0) {
    int acc = 0;
    for (int i = 0; i < 512; ++i) {
      int x = part[i];
      part[i] = acc;
      acc += x;
    }
  }
  __syncthreads();
  int run = part[t];
  for (int i = 0; i < per; ++i) {
    int idx = s0 + i;
    if (idx < nbuk) {
      bbase[idx] = run;
      bcursor_pad[idx * PAD] = run;
      run += vals[idx];
    }
  }
  if (t == 511) bbase[nbuk] = run;
}

// ---------- 3-phase LDS-staged partition into 512-row buckets ----------
__global__ __launch_bounds__(256) void partition_lds_kernel(
    const float* __restrict__ vals, const int* __restrict__ rows,
    const int* __restrict__ cols, int* __restrict__ bcursor_pad,
    int2* __restrict__ tmp, int nnz, int nbuk) {
  __shared__ int h[MAXBUK];
  __shared__ int cur[MAXBUK];
  for (int i = threadIdx.x; i < nbuk; i += 256) h[i] = 0;
  __syncthreads();

  int base = blockIdx.x * CHUNK;
  int rw[EPT], cl[EPT];
  float vl[EPT];
#pragma unroll
  for (int u = 0; u < EPT; ++u) {
    int ii = base + u * 256 + (int)threadIdx.x;
    bool ok = ii < nnz;
    rw[u] = ok ? rows[ii] : -1;
    cl[u] = ok ? cols[ii] : 0;
    vl[u] = ok ? vals[ii] : 0.0f;
    if (ok) atomicAdd(&h[rw[u] >> RSHIFT], 1);
  }
  __syncthreads();
  for (int b = threadIdx.x; b < nbuk; b += 256) {
    int c = h[b];
    cur[b] = c ? atomicAdd(&bcursor_pad[b * PAD], c) : 0;
  }
  __syncthreads();
#pragma unroll
  for (int u = 0; u < EPT; ++u) {
    if (rw[u] >= 0) {
      int b = rw[u] >> RSHIFT;
      int pos = atomicAdd(&cur[b], 1);
      tmp[pos] = make_int2(__float_as_int(vl[u]),
                           ((rw[u] & (SUBR - 1)) << 17) | cl[u]);
    }
  }
}

// ---------- per-bucket row sort -> final CSR (edges + row_ptr) ----------
// one block per 512-row bucket (~13K edges, ~104KB window, L2-resident)
__global__ __launch_bounds__(256) void bucket_sort_kernel(
    const int2* __restrict__ tmp, const int* __restrict__ bbase,
    int2* __restrict__ edges, int* __restrict__ row_ptr, int nrows) {
  __shared__ int h[SUBR];
  __shared__ int ex[SUBR];
  __shared__ int part[256];
  int b = blockIdx.x;
  int s = bbase[b], e = bbase[b + 1];
  int t = threadIdx.x;
  for (int j = t; j < SUBR; j += 256) h[j] = 0;
  __syncthreads();
  for (int i = s + t; i < e; i += 256)
    atomicAdd(&h[((unsigned)tmp[i].y) >> 17], 1);
  __syncthreads();
  part[t] = h[t * 2] + h[t * 2 + 1];
  __syncthreads();
  if (t == 0) {
    int acc = 0;
    for (int i = 0; i < 256; ++i) {
      int x = part[i];
      part[i] = acc;
      acc += x;
    }
  }
  __syncthreads();
  {
    int run = part[t];
    ex[t * 2] = run;
    ex[t * 2 + 1] = run + h[t * 2];
  }
  __syncthreads();
  int r0 = b << RSHIFT;
  int total = e - s;
  for (int j = t; j <= SUBR; j += 256) {
    int r = r0 + j;
    if ((j < SUBR && r < nrows) || r == nrows)
      row_ptr[r] = s + ((j < SUBR) ? ex[j] : total);
  }
  for (int j = t; j < SUBR; j += 256) h[j] = ex[j];  // cursors
  __syncthreads();
  for (int i = s + t; i < e; i += 256) {
    int2 tv = tmp[i];
    int rl = ((unsigned)tv.y) >> 17;
    int p = atomicAdd(&h[rl], 1);
    edges[s + p] = make_int2(tv.x, tv.y & 0x1FFFF);
  }
}

// ---------- CSR SpMM: one wave per row, lane = dim, bf16 gathers ----------
// Fixed 16-wide chunks, uniform index-clamp instead of a serial tail:
// every chunk issues 16 gathers back-to-back (clamped dups hit a line already
// in flight); inactive terms use v=0 so the fp32 chain is bit-identical.
__global__ __launch_bounds__(256) void spmm_csr_kernel(
    const int* __restrict__ rp, const int2* __restrict__ edges,
    const unsigned short* __restrict__ egobf, float* __restrict__ side,
    int nrows) {
  int lane = threadIdx.x & 63;
  int r = blockIdx.x * (blockDim.x >> 6) + (threadIdx.x >> 6);
  if (r >= nrows) return;
  int start = rp[r], end = rp[r + 1];
  float acc = 0.0f;
  for (int base = start; base < end; base += 64) {
    int m = end - base;
    if (m > 64) m = 64;
    int2 e = (base + lane < end) ? edges[base + lane] : make_int2(0, 0);
    float v_l = __int_as_float(e.x);
    int c_l = e.y;
    for (int kk = 0; kk < m; kk += 16) {
      int c[16];
      float v[16], x[16];
#pragma unroll
      for (int u = 0; u < 16; ++u) {
        int idx = (kk + u < m) ? (kk + u) : kk;  // uniform clamp
        c[u] = readlane_i(c_l, idx);
        v[u] = (kk + u < m) ? readlane_f(v_l, idx) : 0.0f;
      }
#pragma unroll
      for (int u = 0; u < 16; ++u)
        x[u] = bf16_to_f32(egobf[(size_t)c[u] * EMB + lane]);
#pragma unroll
      for (int u = 0; u < 16; ++u) acc = fmaf(v[u], x[u], acc);
    }
  }
  side[(size_t)r * EMB + lane] = acc;
}

// per row: sum = side@Wgc + bgc ; bi = (ego*side)@Wbi + bbi ;
// ego_new = leaky_relu(sum+bi, 0.2) (UNNORMALIZED -> ego/egobf);
// all_emb[:, col_off:+64] = ego_new / max(||ego_new||, 1e-12)
__global__ __launch_bounds__(256) void layer_fused_kernel(
    const float* __restrict__ side, float* ego, unsigned short* __restrict__ egobf,
    const float* __restrict__ Wgc, const float* __restrict__ bgc,
    const float* __restrict__ Wbi, const float* __restrict__ bbi,
    float* __restrict__ all_emb, int nrows, int col_off) {
  int lane = threadIdx.x & 63;
  float wgc[EMB], wbi[EMB];
#pragma unroll
  for (int kk = 0; kk < EMB; ++kk) {
    wgc[kk] = Wgc[kk * EMB + lane];
    wbi[kk] = Wbi[kk * EMB + lane];
  }
  float bg = bgc[lane], bb = bbi[lane];
  int wid = blockIdx.x * (blockDim.x >> 6) + (threadIdx.x >> 6);
  int nw = gridDim.x * (blockDim.x >> 6);
  for (int r = wid; r < nrows; r += nw) {
    float s = side[(size_t)r * EMB + lane];
    float e = ego[(size_t)r * EMB + lane];
    float es = e * s;
    float g0 = 0.f, g1 = 0.f, g2 = 0.f, g3 = 0.f;
    float h0 = 0.f, h1 = 0.f, h2 = 0.f, h3 = 0.f;
#pragma unroll
    for (int kk = 0; kk < EMB; kk += 4) {
      g0 = fmaf(readlane_f(s, kk + 0), wgc[kk + 0], g0);
      g1 = fmaf(readlane_f(s, kk + 1), wgc[kk + 1], g1);
      g2 = fmaf(readlane_f(s, kk + 2), wgc[kk + 2], g2);
      g3 = fmaf(readlane_f(s, kk + 3), wgc[kk + 3], g3);
      h0 = fmaf(readlane_f(es, kk + 0), wbi[kk + 0], h0);
      h1 = fmaf(readlane_f(es, kk + 1), wbi[kk + 1], h1);
      h2 = fmaf(readlane_f(es, kk + 2), wbi[kk + 2], h2);
      h3 = fmaf(readlane_f(es, kk + 3), wbi[kk + 3], h3);
    }
    float o = (((g0 + g1) + (g2 + g3)) + bg) + (((h0 + h1) + (h2 + h3)) + bb);
    o = (o >= 0.0f) ? o : 0.2f * o;
    ego[(size_t)r * EMB + lane] = o;
    egobf[(size_t)r * EMB + lane] = f32_to_bf16(o);
    float sq = o * o;
#pragma unroll
    for (int off = 32; off; off >>= 1) sq += __shfl_xor(sq, off, 64);
    float norm = fmaxf(sqrtf(sq), 1e-12f);
    all_emb[(size_t)r * OUT_D + col_off + lane] = o / norm;
  }
}

__global__ void gather_out_kernel(const float* __restrict__ all_emb,
                                  const int* __restrict__ users,
                                  const int* __restrict__ pos,
                                  const int* __restrict__ neg,
                                  float* __restrict__ out, int n_users, int B) {
  int row = blockIdx.x;
  int sec = blockIdx.y;
  int t = threadIdx.x;
  int src;
  if (sec == 0) src = users[row];
  else if (sec == 1) src = n_users + pos[row];
  else src = n_users + neg[row];
  out[((size_t)sec * B + row) * OUT_D + t] = all_emb[(size_t)src * OUT_D + t];
}

extern "C" void kernel_launch(void* const* d_in, const int* in_sizes, int n_in,
                              void* d_out, int out_size, void* d_ws, size_t ws_size,
                              hipStream_t stream) {
  const float* user_emb = (const float*)d_in[0];
  const float* item_emb = (const float*)d_in[1];
  const float* W_gc = (const float*)d_in[2];
  const float* b_gc = (const float*)d_in[3];
  const float* W_bi = (const float*)d_in[4];
  const float* b_bi = (const float*)d_in[5];
  const float* adj_vals = (const float*)d_in[6];
  const int* adj_rows = (const int*)d_in[7];
  const int* adj_cols = (const int*)d_in[8];
  const int* user_sizes = (const int*)d_in[9];
  const int* item_sizes = (const int*)d_in[10];
  const int* users = (const int*)d_in[11];
  const int* pos_items = (const int*)d_in[12];
  const int* neg_items = (const int*)d_in[13];

  const int n_users = in_sizes[9];
  const int n_items = in_sizes[10];
  const int N = n_users + n_items;
  const int nnz = in_sizes[6];
  const int B = in_sizes[11];
  const int nbuk = (N + SUBR - 1) / SUBR;  // 196 for N=100000

  // workspace layout:
  // all_emb [N*256]f (tmp int2[nnz] aliases its head during build)
  // | ego [N*64]f | side [N*64]f | row_ptr [N+1]i | bbase [nbuk+1]i |
  // bcnt_pad [nbuk*PAD]i | bcursor_pad [nbuk*PAD]i | (align 8) edges [nnz]int2
  // | egobf [N*64]u16
  float* all_emb = (float*)d_ws;
  float* ego = all_emb + (size_t)N * OUT_D;
  float* side = ego + (size_t)N * EMB;
  int* row_ptr = (int*)(side + (size_t)N * EMB);
  int* bbase = row_ptr + (N + 1);
  int* bcnt_pad = bbase + (nbuk + 1);
  int* bcursor_pad = bcnt_pad + (size_t)nbuk * PAD;
  int2* edges = (int2*)((((uintptr_t)(bcursor_pad + (size_t)nbuk * PAD)) + 7) &
                        ~(uintptr_t)7);
  unsigned short* egobf = (unsigned short*)(edges + nnz);
  int2* tmp = (int2*)all_emb;  // aliased; init_ego runs after the build

  // --- build row-sorted CSR (bucket partition + per-bucket sort) ---
  hipMemsetAsync(bcnt_pad, 0, (size_t)nbuk * PAD * sizeof(int), stream);
  hipLaunchKernelGGL(bucket_hist_kernel, dim3(512), dim3(256), 0, stream,
                     adj_rows, bcnt_pad, nnz, nbuk);
  hipLaunchKernelGGL(bucket_scan_kernel, dim3(1), dim3(512), 0, stream,
                     bcnt_pad, bbase, bcursor_pad, nbuk);
  {
    int nchunks = (nnz + CHUNK - 1) / CHUNK;
    hipLaunchKernelGGL(partition_lds_kernel, dim3(nchunks), dim3(256), 0,
                       stream, adj_vals, adj_rows, adj_cols, bcursor_pad, tmp,
                       nnz, nbuk);
  }
  hipLaunchKernelGGL(bucket_sort_kernel, dim3(nbuk), dim3(256), 0, stream, tmp,
                     bbase, edges, row_ptr, N);

  // --- init ego (+bf16 shadow) + all_emb block 0 ---
  {
    int total = N * EMB;
    hipLaunchKernelGGL(init_ego_kernel, dim3((total + 255) / 256), dim3(256), 0,
                       stream, user_emb, item_emb, user_sizes, item_sizes, ego,
                       egobf, all_emb, n_users, N);
  }

  // --- 3 propagation layers ---
  for (int k = 0; k < N_LAYERS; ++k) {
    hipLaunchKernelGGL(spmm_csr_kernel, dim3((N + 3) / 4), dim3(256), 0, stream,
                       row_ptr, edges, egobf, side, N);
    hipLaunchKernelGGL(layer_fused_kernel, dim3(4096), dim3(256), 0, stream,
                       side, ego, egobf, W_gc + k * EMB * EMB, b_gc + k * EMB,
                       W_bi + k * EMB * EMB, b_bi + k * EMB, all_emb, N,
                       (k + 1) * EMB);
  }

  hipLaunchKernelGGL(gather_out_kernel, dim3(B, 3), dim3(256), 0, stream,
                     all_emb, users, pos_items, neg_items, (float*)d_out,
                     n_users, B);
}